// Round 1
// baseline (220.304 us; speedup 1.0000x reference)
//
#include <hip/hip_runtime.h>
#include <hip/hip_bf16.h>

#define BM 32

// ---------------------------------------------------------------------------
// K1: XL = x @ Wl + bl ; XR = x @ Wr + br   (blockIdx.y selects which)
// x: [n,128], W: [128,128], out: [n,128]
// ---------------------------------------------------------------------------
__global__ __launch_bounds__(256) void gemm2(
    const float* __restrict__ x,
    const float* __restrict__ Wl, const float* __restrict__ bl, float* __restrict__ XL,
    const float* __restrict__ Wr, const float* __restrict__ br, float* __restrict__ XR,
    int n)
{
    const float* W = blockIdx.y ? Wr : Wl;
    const float* b = blockIdx.y ? br : bl;
    float*       O = blockIdx.y ? XR : XL;

    __shared__ float xT[128][36];   // transposed x tile, padded stride 36 (16B-aligned rows, conflict-free)

    const int tid  = threadIdx.x;
    const int row0 = blockIdx.x * BM;

    // stage x[row0..row0+31][:] transposed into LDS
    {
        const int r  = tid & 31;
        const int kb = (tid >> 5) * 16;
        if (row0 + r < n) {
            const float* xr = &x[(size_t)(row0 + r) * 128 + kb];
            #pragma unroll
            for (int j = 0; j < 16; j += 4) {
                float4 v = *(const float4*)&xr[j];
                xT[kb + j + 0][r] = v.x;
                xT[kb + j + 1][r] = v.y;
                xT[kb + j + 2][r] = v.z;
                xT[kb + j + 3][r] = v.w;
            }
        } else {
            #pragma unroll
            for (int j = 0; j < 16; ++j) xT[kb + j][r] = 0.f;
        }
    }
    __syncthreads();

    const int c4 = (tid & 31) * 4;   // output col group
    const int r4 = (tid >> 5) * 4;   // output row group (within tile)

    float4 acc0 = {0,0,0,0}, acc1 = {0,0,0,0}, acc2 = {0,0,0,0}, acc3 = {0,0,0,0};

    #pragma unroll 4
    for (int k = 0; k < 128; ++k) {
        float4 wv = *(const float4*)&W[k * 128 + c4];
        float4 av = *(const float4*)&xT[k][r4];
        acc0.x += av.x * wv.x; acc0.y += av.x * wv.y; acc0.z += av.x * wv.z; acc0.w += av.x * wv.w;
        acc1.x += av.y * wv.x; acc1.y += av.y * wv.y; acc1.z += av.y * wv.z; acc1.w += av.y * wv.w;
        acc2.x += av.z * wv.x; acc2.y += av.z * wv.y; acc2.z += av.z * wv.z; acc2.w += av.z * wv.w;
        acc3.x += av.w * wv.x; acc3.y += av.w * wv.y; acc3.z += av.w * wv.z; acc3.w += av.w * wv.w;
    }

    float4 bv = *(const float4*)&b[c4];
    acc0.x += bv.x; acc0.y += bv.y; acc0.z += bv.z; acc0.w += bv.w;
    acc1.x += bv.x; acc1.y += bv.y; acc1.z += bv.z; acc1.w += bv.w;
    acc2.x += bv.x; acc2.y += bv.y; acc2.z += bv.z; acc2.w += bv.w;
    acc3.x += bv.x; acc3.y += bv.y; acc3.z += bv.z; acc3.w += bv.w;

    if (row0 + r4 + 0 < n) *(float4*)&O[(size_t)(row0 + r4 + 0) * 128 + c4] = acc0;
    if (row0 + r4 + 1 < n) *(float4*)&O[(size_t)(row0 + r4 + 1) * 128 + c4] = acc1;
    if (row0 + r4 + 2 < n) *(float4*)&O[(size_t)(row0 + r4 + 2) * 128 + c4] = acc2;
    if (row0 + r4 + 3 < n) *(float4*)&O[(size_t)(row0 + r4 + 3) * 128 + c4] = acc3;
}

// ---------------------------------------------------------------------------
// K2: per edge (incl. self-loops): logit = att . lrelu(xl[src]+xr[dst]),
//     w = exp(logit), denom[dst] += w.  One 32-lane half-wave per edge.
// ---------------------------------------------------------------------------
__global__ __launch_bounds__(256) void edge_logits(
    const float* __restrict__ XL, const float* __restrict__ XR,
    const int* __restrict__ ei, const float* __restrict__ att,
    float* __restrict__ wbuf, float* __restrict__ denom,
    int nE, int nTot)
{
    const int e = (blockIdx.x * 256 + threadIdx.x) >> 5;
    if (e >= nTot) return;
    const int sub = threadIdx.x & 31;

    int src, dst;
    if (e < nE) { src = ei[e]; dst = ei[nE + e]; }
    else        { src = dst = e - nE; }

    float4 xlv = *(const float4*)&XL[(size_t)src * 128 + sub * 4];
    float4 xrv = *(const float4*)&XR[(size_t)dst * 128 + sub * 4];
    float4 s;
    s.x = xlv.x + xrv.x; s.y = xlv.y + xrv.y; s.z = xlv.z + xrv.z; s.w = xlv.w + xrv.w;
    s.x = s.x > 0.f ? s.x : 0.2f * s.x;
    s.y = s.y > 0.f ? s.y : 0.2f * s.y;
    s.z = s.z > 0.f ? s.z : 0.2f * s.z;
    s.w = s.w > 0.f ? s.w : 0.2f * s.w;

    float4 av = *(const float4*)&att[sub * 4];
    float p = s.x * av.x + s.y * av.y + s.z * av.z + s.w * av.w;

    #pragma unroll
    for (int m = 16; m >= 1; m >>= 1) p += __shfl_xor(p, m);

    if (sub == 0) {
        float wv = __expf(p);           // logits are small; no max-shift needed
        wbuf[e] = wv;
        atomicAdd(&denom[dst], wv);
    }
}

// ---------------------------------------------------------------------------
// K3: S[0:128] += sum_e (w[e]/denom[dst]) * xl[src].  Grid-stride half-waves.
// ---------------------------------------------------------------------------
__global__ __launch_bounds__(256) void edge_accum(
    const float* __restrict__ XL, const int* __restrict__ ei,
    const float* __restrict__ wbuf, const float* __restrict__ denom,
    float* __restrict__ S, int nE, int nTot)
{
    const int sub   = threadIdx.x & 31;
    const int hwLoc = threadIdx.x >> 5;           // 0..7
    const int hw0   = blockIdx.x * 8 + hwLoc;
    const int strd  = gridDim.x * 8;

    float4 acc = {0,0,0,0};
    for (int e = hw0; e < nTot; e += strd) {
        int src, dst;
        if (e < nE) { src = ei[e]; dst = ei[nE + e]; }
        else        { src = dst = e - nE; }
        float coeff = wbuf[e] / denom[dst];
        float4 xlv = *(const float4*)&XL[(size_t)src * 128 + sub * 4];
        acc.x += coeff * xlv.x; acc.y += coeff * xlv.y;
        acc.z += coeff * xlv.z; acc.w += coeff * xlv.w;
    }

    // combine the two half-waves of each wave (lanes l and l+32 map same dims)
    acc.x += __shfl_xor(acc.x, 32);
    acc.y += __shfl_xor(acc.y, 32);
    acc.z += __shfl_xor(acc.z, 32);
    acc.w += __shfl_xor(acc.w, 32);

    __shared__ float sbuf[4][128];
    const int wave = threadIdx.x >> 6;            // 0..3
    if ((threadIdx.x & 63) < 32) *(float4*)&sbuf[wave][sub * 4] = acc;
    __syncthreads();

    if (threadIdx.x < 128) {
        float t = sbuf[0][threadIdx.x] + sbuf[1][threadIdx.x]
                + sbuf[2][threadIdx.x] + sbuf[3][threadIdx.x];
        atomicAdd(&S[threadIdx.x], t);
    }
}

// ---------------------------------------------------------------------------
// K4: g = BN_affine(S/n + bias1); out = softmax(g @ Wc + bc)
// ---------------------------------------------------------------------------
__global__ __launch_bounds__(128) void finalize(
    const float* __restrict__ S, const float* __restrict__ bias1,
    const float* __restrict__ gamma, const float* __restrict__ beta,
    const float* __restrict__ mean, const float* __restrict__ var,
    const float* __restrict__ Wc, const float* __restrict__ bc,
    float* __restrict__ out, int n)
{
    __shared__ float g[128];
    __shared__ float lg[5];
    const int t = threadIdx.x;

    float gv = (S[t] / (float)n + bias1[t] - mean[t])
             * rsqrtf(var[t] + 1e-5f) * gamma[t] + beta[t];
    g[t] = gv;
    __syncthreads();

    if (t < 5) {
        float acc = bc[t];
        #pragma unroll 16
        for (int d = 0; d < 128; ++d) acc += g[d] * Wc[d * 5 + t];
        lg[t] = acc;
    }
    __syncthreads();

    if (t == 0) {
        float m = lg[0];
        #pragma unroll
        for (int i = 1; i < 5; ++i) m = fmaxf(m, lg[i]);
        float ex[5]; float sum = 0.f;
        #pragma unroll
        for (int i = 0; i < 5; ++i) { ex[i] = expf(lg[i] - m); sum += ex[i]; }
        #pragma unroll
        for (int i = 0; i < 5; ++i) out[i] = ex[i] / sum;
    }
}

// ---------------------------------------------------------------------------
extern "C" void kernel_launch(void* const* d_in, const int* in_sizes, int n_in,
                              void* d_out, int out_size, void* d_ws, size_t ws_size,
                              hipStream_t stream)
{
    const float* x     = (const float*)d_in[0];
    const int*   ei    = (const int*)  d_in[1];
    const float* Wl    = (const float*)d_in[2];
    const float* bl    = (const float*)d_in[3];
    const float* Wr    = (const float*)d_in[4];
    const float* br    = (const float*)d_in[5];
    const float* att   = (const float*)d_in[6];
    const float* bias1 = (const float*)d_in[7];
    const float* gamma = (const float*)d_in[8];
    const float* beta  = (const float*)d_in[9];
    const float* mean  = (const float*)d_in[10];
    const float* var   = (const float*)d_in[11];
    const float* Wc    = (const float*)d_in[12];
    const float* bc    = (const float*)d_in[13];

    const int n    = in_sizes[0] / 128;
    const int nE   = in_sizes[1] / 2;
    const int nTot = nE + n;

    float* XL    = (float*)d_ws;                       // n*128
    float* XR    = XL + (size_t)n * 128;               // n*128
    float* wbuf  = XR + (size_t)n * 128;               // nTot
    float* denom = wbuf + nTot;                        // n
    float* S     = denom + n;                          // 128

    // zero denom + S (contiguous)
    hipMemsetAsync(denom, 0, (size_t)(n + 128) * sizeof(float), stream);

    dim3 g1((n + BM - 1) / BM, 2);
    gemm2<<<g1, 256, 0, stream>>>(x, Wl, bl, XL, Wr, br, XR, n);

    int b2 = (nTot + 7) / 8;
    edge_logits<<<b2, 256, 0, stream>>>(XL, XR, ei, att, wbuf, denom, nE, nTot);

    edge_accum<<<1024, 256, 0, stream>>>(XL, ei, wbuf, denom, S, nE, nTot);

    finalize<<<1, 128, 0, stream>>>(S, bias1, gamma, beta, mean, var, Wc, bc,
                                    (float*)d_out, n);
}

// Round 2
// 169.836 us; speedup vs baseline: 1.2972x; 1.2972x over previous
//
#include <hip/hip_runtime.h>
#include <hip/hip_bf16.h>

#define BM 32

__device__ __forceinline__ unsigned short f2b(float f) {
    union { float f; unsigned int u; } v; v.f = f;
    unsigned int r = (v.u + 0x7fffu + ((v.u >> 16) & 1u)) >> 16;
    return (unsigned short)r;
}
__device__ __forceinline__ unsigned int pack2(float lo, float hi) {
    return (unsigned int)f2b(lo) | ((unsigned int)f2b(hi) << 16);
}
__device__ __forceinline__ void unpack2(unsigned int u, float& a, float& b) {
    a = __uint_as_float(u << 16);
    b = __uint_as_float(u & 0xffff0000u);
}

// ---------------------------------------------------------------------------
// K1: XLh = bf16(x @ Wl + bl), XRh = bf16(x @ Wr + br). Both in one block so
// x is read once. 32-row tile, 4x4 register blocking per thread.
// ---------------------------------------------------------------------------
__global__ __launch_bounds__(256) void gemm2(
    const float* __restrict__ x,
    const float* __restrict__ Wl, const float* __restrict__ bl, unsigned short* __restrict__ XLh,
    const float* __restrict__ Wr, const float* __restrict__ br, unsigned short* __restrict__ XRh,
    int n)
{
    __shared__ float xT[128][36];   // transposed x tile, padded

    const int tid  = threadIdx.x;
    const int row0 = blockIdx.x * BM;

    {
        const int r  = tid & 31;
        const int kb = (tid >> 5) * 16;
        if (row0 + r < n) {
            const float* xr = &x[(size_t)(row0 + r) * 128 + kb];
            #pragma unroll
            for (int j = 0; j < 16; j += 4) {
                float4 v = *(const float4*)&xr[j];
                xT[kb + j + 0][r] = v.x;
                xT[kb + j + 1][r] = v.y;
                xT[kb + j + 2][r] = v.z;
                xT[kb + j + 3][r] = v.w;
            }
        } else {
            #pragma unroll
            for (int j = 0; j < 16; ++j) xT[kb + j][r] = 0.f;
        }
    }
    __syncthreads();

    const int c4 = (tid & 31) * 4;
    const int r4 = (tid >> 5) * 4;

    float4 aL0{0,0,0,0}, aL1{0,0,0,0}, aL2{0,0,0,0}, aL3{0,0,0,0};
    float4 aR0{0,0,0,0}, aR1{0,0,0,0}, aR2{0,0,0,0}, aR3{0,0,0,0};

    #pragma unroll 2
    for (int k = 0; k < 128; ++k) {
        float4 wl = *(const float4*)&Wl[k * 128 + c4];
        float4 wr = *(const float4*)&Wr[k * 128 + c4];
        float4 av = *(const float4*)&xT[k][r4];
        aL0.x += av.x * wl.x; aL0.y += av.x * wl.y; aL0.z += av.x * wl.z; aL0.w += av.x * wl.w;
        aL1.x += av.y * wl.x; aL1.y += av.y * wl.y; aL1.z += av.y * wl.z; aL1.w += av.y * wl.w;
        aL2.x += av.z * wl.x; aL2.y += av.z * wl.y; aL2.z += av.z * wl.z; aL2.w += av.z * wl.w;
        aL3.x += av.w * wl.x; aL3.y += av.w * wl.y; aL3.z += av.w * wl.z; aL3.w += av.w * wl.w;
        aR0.x += av.x * wr.x; aR0.y += av.x * wr.y; aR0.z += av.x * wr.z; aR0.w += av.x * wr.w;
        aR1.x += av.y * wr.x; aR1.y += av.y * wr.y; aR1.z += av.y * wr.z; aR1.w += av.y * wr.w;
        aR2.x += av.z * wr.x; aR2.y += av.z * wr.y; aR2.z += av.z * wr.z; aR2.w += av.z * wr.w;
        aR3.x += av.w * wr.x; aR3.y += av.w * wr.y; aR3.z += av.w * wr.z; aR3.w += av.w * wr.w;
    }

    float4 blv = *(const float4*)&bl[c4];
    float4 brv = *(const float4*)&br[c4];

    #define STORE_ROW(acc, bv, Oh, ri)                                            \
        if (row0 + r4 + ri < n) {                                                 \
            uint2 p;                                                              \
            p.x = pack2(acc.x + bv.x, acc.y + bv.y);                              \
            p.y = pack2(acc.z + bv.z, acc.w + bv.w);                              \
            *(uint2*)&Oh[(size_t)(row0 + r4 + ri) * 128 + c4] = p;                \
        }
    STORE_ROW(aL0, blv, XLh, 0) STORE_ROW(aL1, blv, XLh, 1)
    STORE_ROW(aL2, blv, XLh, 2) STORE_ROW(aL3, blv, XLh, 3)
    STORE_ROW(aR0, brv, XRh, 0) STORE_ROW(aR1, brv, XRh, 1)
    STORE_ROW(aR2, brv, XRh, 2) STORE_ROW(aR3, brv, XRh, 3)
    #undef STORE_ROW
}

// ---------------------------------------------------------------------------
// K2: per edge: logit = att . lrelu(xl[src]+xr[dst]); w=exp(logit);
//     denom[dst] += w.   16 lanes per edge, bf16 gathers (256B/row).
// ---------------------------------------------------------------------------
__global__ __launch_bounds__(256) void edge_logits(
    const unsigned short* __restrict__ XLh, const unsigned short* __restrict__ XRh,
    const int* __restrict__ ei, const float* __restrict__ att,
    float* __restrict__ wbuf, float* __restrict__ denom,
    int nE, int nTot)
{
    const int e = (blockIdx.x * 256 + threadIdx.x) >> 4;
    if (e >= nTot) return;
    const int sub = threadIdx.x & 15;

    int src, dst;
    if (e < nE) { src = ei[e]; dst = ei[nE + e]; }
    else        { src = dst = e - nE; }

    uint4 ul = *(const uint4*)&XLh[(size_t)src * 128 + sub * 8];
    uint4 ur = *(const uint4*)&XRh[(size_t)dst * 128 + sub * 8];
    float4 a0 = *(const float4*)&att[sub * 8];
    float4 a1 = *(const float4*)&att[sub * 8 + 4];

    float l0,l1,l2,l3,l4,l5,l6,l7, r0,r1,r2,r3,r4,r5,r6,r7;
    unpack2(ul.x, l0, l1); unpack2(ul.y, l2, l3);
    unpack2(ul.z, l4, l5); unpack2(ul.w, l6, l7);
    unpack2(ur.x, r0, r1); unpack2(ur.y, r2, r3);
    unpack2(ur.z, r4, r5); unpack2(ur.w, r6, r7);

    float s0=l0+r0, s1=l1+r1, s2=l2+r2, s3=l3+r3;
    float s4=l4+r4, s5=l5+r5, s6=l6+r6, s7=l7+r7;
    s0 = s0 > 0.f ? s0 : 0.2f*s0;  s1 = s1 > 0.f ? s1 : 0.2f*s1;
    s2 = s2 > 0.f ? s2 : 0.2f*s2;  s3 = s3 > 0.f ? s3 : 0.2f*s3;
    s4 = s4 > 0.f ? s4 : 0.2f*s4;  s5 = s5 > 0.f ? s5 : 0.2f*s5;
    s6 = s6 > 0.f ? s6 : 0.2f*s6;  s7 = s7 > 0.f ? s7 : 0.2f*s7;

    float p = s0*a0.x + s1*a0.y + s2*a0.z + s3*a0.w
            + s4*a1.x + s5*a1.y + s6*a1.z + s7*a1.w;

    #pragma unroll
    for (int m = 8; m >= 1; m >>= 1) p += __shfl_xor(p, m);

    if (sub == 0) {
        float wv = __expf(p);     // logits are O(1); softmax shift-invariant
        wbuf[e] = wv;
        atomicAdd(&denom[dst], wv);
    }
}

// ---------------------------------------------------------------------------
// K3a: c[src] += w[e] / denom[dst]   (scalar per edge; tables are L2-resident)
// ---------------------------------------------------------------------------
__global__ __launch_bounds__(256) void edge_coeff(
    const int* __restrict__ ei, const float* __restrict__ wbuf,
    const float* __restrict__ denom, float* __restrict__ csrc,
    int nE, int nTot)
{
    const int e = blockIdx.x * 256 + threadIdx.x;
    if (e >= nTot) return;
    int src, dst;
    if (e < nE) { src = ei[e]; dst = ei[nE + e]; }
    else        { src = dst = e - nE; }
    atomicAdd(&csrc[src], wbuf[e] / denom[dst]);
}

// ---------------------------------------------------------------------------
// K3b: S = sum_j c[j] * xl[j]   (dense bf16 stream, no gathers)
// ---------------------------------------------------------------------------
__global__ __launch_bounds__(256) void wsum(
    const unsigned short* __restrict__ XLh, const float* __restrict__ csrc,
    float* __restrict__ S, int n)
{
    const int sub = threadIdx.x & 15;      // feature group (8 feats)
    const int grp = threadIdx.x >> 4;      // 0..15: node within block slice
    const int strd = gridDim.x * 16;

    float acc[8] = {0,0,0,0,0,0,0,0};
    for (int j = blockIdx.x * 16 + grp; j < n; j += strd) {
        float cj = csrc[j];
        uint4 u = *(const uint4*)&XLh[(size_t)j * 128 + sub * 8];
        float f0,f1,f2,f3,f4,f5,f6,f7;
        unpack2(u.x, f0, f1); unpack2(u.y, f2, f3);
        unpack2(u.z, f4, f5); unpack2(u.w, f6, f7);
        acc[0] += cj*f0; acc[1] += cj*f1; acc[2] += cj*f2; acc[3] += cj*f3;
        acc[4] += cj*f4; acc[5] += cj*f5; acc[6] += cj*f6; acc[7] += cj*f7;
    }

    __shared__ float sb[16][128];
    #pragma unroll
    for (int k = 0; k < 8; k += 4)
        *(float4*)&sb[grp][sub * 8 + k] = make_float4(acc[k], acc[k+1], acc[k+2], acc[k+3]);
    __syncthreads();

    if (threadIdx.x < 128) {
        float t = 0.f;
        #pragma unroll
        for (int g = 0; g < 16; ++g) t += sb[g][threadIdx.x];
        atomicAdd(&S[threadIdx.x], t);
    }
}

// ---------------------------------------------------------------------------
// K4: g = BN_affine(S/n + bias1); out = softmax(g @ Wc + bc)
// ---------------------------------------------------------------------------
__global__ __launch_bounds__(128) void finalize(
    const float* __restrict__ S, const float* __restrict__ bias1,
    const float* __restrict__ gamma, const float* __restrict__ beta,
    const float* __restrict__ mean, const float* __restrict__ var,
    const float* __restrict__ Wc, const float* __restrict__ bc,
    float* __restrict__ out, int n)
{
    __shared__ float g[128];
    __shared__ float lg[5];
    const int t = threadIdx.x;

    float gv = (S[t] / (float)n + bias1[t] - mean[t])
             * rsqrtf(var[t] + 1e-5f) * gamma[t] + beta[t];
    g[t] = gv;
    __syncthreads();

    if (t < 5) {
        float acc = bc[t];
        #pragma unroll 16
        for (int d = 0; d < 128; ++d) acc += g[d] * Wc[d * 5 + t];
        lg[t] = acc;
    }
    __syncthreads();

    if (t == 0) {
        float m = lg[0];
        #pragma unroll
        for (int i = 1; i < 5; ++i) m = fmaxf(m, lg[i]);
        float ex[5]; float sum = 0.f;
        #pragma unroll
        for (int i = 0; i < 5; ++i) { ex[i] = expf(lg[i] - m); sum += ex[i]; }
        #pragma unroll
        for (int i = 0; i < 5; ++i) out[i] = ex[i] / sum;
    }
}

// ---------------------------------------------------------------------------
extern "C" void kernel_launch(void* const* d_in, const int* in_sizes, int n_in,
                              void* d_out, int out_size, void* d_ws, size_t ws_size,
                              hipStream_t stream)
{
    const float* x     = (const float*)d_in[0];
    const int*   ei    = (const int*)  d_in[1];
    const float* Wl    = (const float*)d_in[2];
    const float* bl    = (const float*)d_in[3];
    const float* Wr    = (const float*)d_in[4];
    const float* br    = (const float*)d_in[5];
    const float* att   = (const float*)d_in[6];
    const float* bias1 = (const float*)d_in[7];
    const float* gamma = (const float*)d_in[8];
    const float* beta  = (const float*)d_in[9];
    const float* mean  = (const float*)d_in[10];
    const float* var   = (const float*)d_in[11];
    const float* Wc    = (const float*)d_in[12];
    const float* bc    = (const float*)d_in[13];

    const int n    = in_sizes[0] / 128;
    const int nE   = in_sizes[1] / 2;
    const int nTot = nE + n;

    unsigned short* XLh = (unsigned short*)d_ws;            // n*128 bf16
    unsigned short* XRh = XLh + (size_t)n * 128;            // n*128 bf16
    float* wbuf  = (float*)(XRh + (size_t)n * 128);         // nTot
    float* denom = wbuf + nTot;                             // n
    float* csrc  = denom + n;                               // n
    float* S     = csrc + n;                                // 128

    // zero denom + csrc + S (contiguous)
    hipMemsetAsync(denom, 0, (size_t)(2 * n + 128) * sizeof(float), stream);

    gemm2<<<(n + BM - 1) / BM, 256, 0, stream>>>(x, Wl, bl, XLh, Wr, br, XRh, n);

    edge_logits<<<(nTot * 16 + 255) / 256, 256, 0, stream>>>(
        XLh, XRh, ei, att, wbuf, denom, nE, nTot);

    edge_coeff<<<(nTot + 255) / 256, 256, 0, stream>>>(ei, wbuf, denom, csrc, nE, nTot);

    wsum<<<512, 256, 0, stream>>>(XLh, csrc, S, n);

    finalize<<<1, 128, 0, stream>>>(S, bias1, gamma, beta, mean, var, Wc, bc,
                                    (float*)d_out, n);
}

// Round 3
// 118.438 us; speedup vs baseline: 1.8601x; 1.4340x over previous
//
#include <hip/hip_runtime.h>
#include <hip/hip_bf16.h>

typedef __attribute__((ext_vector_type(8))) short short8v;
typedef __attribute__((ext_vector_type(4))) float f32x4;

__device__ __forceinline__ unsigned short f2b(float f) {
    union { float f; unsigned int u; } v; v.f = f;
    unsigned int r = (v.u + 0x7fffu + ((v.u >> 16) & 1u)) >> 16;
    return (unsigned short)r;
}
__device__ __forceinline__ unsigned int pack2(float lo, float hi) {
    return (unsigned int)f2b(lo) | ((unsigned int)f2b(hi) << 16);
}
__device__ __forceinline__ void unpack2(unsigned int u, float& a, float& b) {
    a = __uint_as_float(u << 16);
    b = __uint_as_float(u & 0xffff0000u);
}

// ---------------------------------------------------------------------------
// K0: pack Wl|Wr (fp32 [128][128] each) into bf16 MFMA-B-fragment order Whf,
// and bh = bl|br (fp32 [256]).
// Whf index: (((ks*16 + nfg)*64 + lane)*8 + j)
//   maps to W[k][c] with k = ks*32 + (lane>>4)*8 + j, c = nfg*16 + (lane&15)
// ---------------------------------------------------------------------------
__global__ __launch_bounds__(256) void prep(
    const float* __restrict__ Wl, const float* __restrict__ bl,
    const float* __restrict__ Wr, const float* __restrict__ br,
    unsigned short* __restrict__ Whf, float* __restrict__ bh)
{
    int idx = blockIdx.x * 256 + threadIdx.x;
    if (idx < 32768) {
        int j   = idx & 7;
        int l   = (idx >> 3) & 63;
        int nfg = (idx >> 9) & 15;
        int ks  = idx >> 13;
        int k = ks * 32 + (l >> 4) * 8 + j;
        int c = nfg * 16 + (l & 15);
        float v = (c < 128) ? Wl[k * 128 + c] : Wr[k * 128 + (c - 128)];
        Whf[idx] = f2b(v);
    } else {
        int c = idx - 32768;
        if (c < 256) bh[c] = (c < 128) ? bl[c] : br[c - 128];
    }
}

// ---------------------------------------------------------------------------
// K1: XLh|XRh = bf16(x @ [Wl|Wr] + [bl|br]) via MFMA.
// Block: 256 thr (4 waves). Tile: 64 rows x 256 cols, K=128.
// Wave w owns cols [w*64, w*64+64). B-frags held in registers (loaded once).
// x tile staged fp32->bf16 into XOR-swizzled LDS.
// ---------------------------------------------------------------------------
#define GBM 64
__global__ __launch_bounds__(256) void gemm_mfma(
    const float* __restrict__ x, const unsigned short* __restrict__ Whf,
    const float* __restrict__ bh,
    unsigned short* __restrict__ XLh, unsigned short* __restrict__ XRh,
    int n, int ntiles)
{
    __shared__ unsigned short xs[GBM * 128];   // 16 KB, swizzled

    const int tid = threadIdx.x;
    const int w   = tid >> 6;       // wave 0..3
    const int l   = tid & 63;
    const int lr  = l & 15;
    const int lk  = l >> 4;

    // load B fragments (coalesced 16B per lane)
    short8v B[4][4];
    #pragma unroll
    for (int ks = 0; ks < 4; ++ks)
        #pragma unroll
        for (int nf = 0; nf < 4; ++nf)
            B[ks][nf] = *(const short8v*)&Whf[(((ks * 16 + (w * 4 + nf)) * 64 + l) << 3)];

    float biasv[4];
    #pragma unroll
    for (int nf = 0; nf < 4; ++nf) biasv[nf] = bh[w * 64 + nf * 16 + lr];

    const int sr  = tid >> 2;            // staging row 0..63
    const int sc0 = (tid & 3) * 32;      // staging col group
    const int swz = (sr & 7) << 4;

    for (int tile = blockIdx.x; tile < ntiles; tile += gridDim.x) {
        const int row0 = tile * GBM;

        // ---- stage x tile (fp32 -> bf16, swizzled) ----
        {
            const int grow = row0 + sr;
            if (grow < n) {
                const float4* src = (const float4*)&x[(size_t)grow * 128 + sc0];
                #pragma unroll
                for (int i = 0; i < 8; ++i) {
                    float4 v = src[i];
                    uint2 p; p.x = pack2(v.x, v.y); p.y = pack2(v.z, v.w);
                    int byte = (sc0 + i * 4) * 2;
                    *(uint2*)((char*)xs + sr * 256 + (byte ^ swz)) = p;
                }
            } else {
                uint2 p{0, 0};
                #pragma unroll
                for (int i = 0; i < 8; ++i) {
                    int byte = (sc0 + i * 4) * 2;
                    *(uint2*)((char*)xs + sr * 256 + (byte ^ swz)) = p;
                }
            }
        }
        __syncthreads();

        // ---- MFMA ----
        f32x4 acc[4][4];
        #pragma unroll
        for (int mf = 0; mf < 4; ++mf)
            #pragma unroll
            for (int nf = 0; nf < 4; ++nf)
                acc[mf][nf] = f32x4{0.f, 0.f, 0.f, 0.f};

        #pragma unroll
        for (int ks = 0; ks < 4; ++ks) {
            short8v A[4];
            #pragma unroll
            for (int mf = 0; mf < 4; ++mf) {
                int rr = mf * 16 + lr;
                int byte = (ks * 32 + lk * 8) * 2;
                A[mf] = *(short8v*)((char*)xs + rr * 256 + (byte ^ ((rr & 7) << 4)));
            }
            #pragma unroll
            for (int mf = 0; mf < 4; ++mf)
                #pragma unroll
                for (int nf = 0; nf < 4; ++nf)
                    acc[mf][nf] = __builtin_amdgcn_mfma_f32_16x16x32_bf16(
                        A[mf], B[ks][nf], acc[mf][nf], 0, 0, 0);
        }

        // ---- epilogue: bias + bf16 store ----
        // C/D: col = lane&15 (within frag), row = lk*4 + j
        unsigned short* O    = (w < 2) ? XLh : XRh;
        const int       oc0  = (w < 2) ? w * 64 : (w - 2) * 64;
        #pragma unroll
        for (int mf = 0; mf < 4; ++mf) {
            #pragma unroll
            for (int nf = 0; nf < 4; ++nf) {
                const int ocol = oc0 + nf * 16 + lr;
                #pragma unroll
                for (int j = 0; j < 4; ++j) {
                    int grow = row0 + mf * 16 + lk * 4 + j;
                    if (grow < n)
                        O[(size_t)grow * 128 + ocol] = f2b(acc[mf][nf][j] + biasv[nf]);
                }
            }
        }
        __syncthreads();
    }
}

// ---------------------------------------------------------------------------
// K2: per edge: logit = att . lrelu(xl[src]+xr[dst]); w=exp(logit);
//     denom[dst] += w.   16 lanes per edge, bf16 gathers.
// ---------------------------------------------------------------------------
__global__ __launch_bounds__(256) void edge_logits(
    const unsigned short* __restrict__ XLh, const unsigned short* __restrict__ XRh,
    const int* __restrict__ ei, const float* __restrict__ att,
    float* __restrict__ wbuf, float* __restrict__ denom,
    int nE, int nTot)
{
    const int e = (blockIdx.x * 256 + threadIdx.x) >> 4;
    if (e >= nTot) return;
    const int sub = threadIdx.x & 15;

    int src, dst;
    if (e < nE) { src = ei[e]; dst = ei[nE + e]; }
    else        { src = dst = e - nE; }

    uint4 ul = *(const uint4*)&XLh[(size_t)src * 128 + sub * 8];
    uint4 ur = *(const uint4*)&XRh[(size_t)dst * 128 + sub * 8];
    float4 a0 = *(const float4*)&att[sub * 8];
    float4 a1 = *(const float4*)&att[sub * 8 + 4];

    float l0,l1,l2,l3,l4,l5,l6,l7, r0,r1,r2,r3,r4,r5,r6,r7;
    unpack2(ul.x, l0, l1); unpack2(ul.y, l2, l3);
    unpack2(ul.z, l4, l5); unpack2(ul.w, l6, l7);
    unpack2(ur.x, r0, r1); unpack2(ur.y, r2, r3);
    unpack2(ur.z, r4, r5); unpack2(ur.w, r6, r7);

    float s0=l0+r0, s1=l1+r1, s2=l2+r2, s3=l3+r3;
    float s4=l4+r4, s5=l5+r5, s6=l6+r6, s7=l7+r7;
    s0 = s0 > 0.f ? s0 : 0.2f*s0;  s1 = s1 > 0.f ? s1 : 0.2f*s1;
    s2 = s2 > 0.f ? s2 : 0.2f*s2;  s3 = s3 > 0.f ? s3 : 0.2f*s3;
    s4 = s4 > 0.f ? s4 : 0.2f*s4;  s5 = s5 > 0.f ? s5 : 0.2f*s5;
    s6 = s6 > 0.f ? s6 : 0.2f*s6;  s7 = s7 > 0.f ? s7 : 0.2f*s7;

    float p = s0*a0.x + s1*a0.y + s2*a0.z + s3*a0.w
            + s4*a1.x + s5*a1.y + s6*a1.z + s7*a1.w;

    #pragma unroll
    for (int m = 8; m >= 1; m >>= 1) p += __shfl_xor(p, m);

    if (sub == 0) {
        float wv = __expf(p);     // logits are O(1); softmax shift-invariant
        wbuf[e] = wv;
        atomicAdd(&denom[dst], wv);
    }
}

// ---------------------------------------------------------------------------
// K3a: c[src] += w[e] / denom[dst]
// ---------------------------------------------------------------------------
__global__ __launch_bounds__(256) void edge_coeff(
    const int* __restrict__ ei, const float* __restrict__ wbuf,
    const float* __restrict__ denom, float* __restrict__ csrc,
    int nE, int nTot)
{
    const int e = blockIdx.x * 256 + threadIdx.x;
    if (e >= nTot) return;
    int src, dst;
    if (e < nE) { src = ei[e]; dst = ei[nE + e]; }
    else        { src = dst = e - nE; }
    atomicAdd(&csrc[src], wbuf[e] / denom[dst]);
}

// ---------------------------------------------------------------------------
// K3b: S = sum_j c[j] * xl[j]   (dense bf16 stream)
// ---------------------------------------------------------------------------
__global__ __launch_bounds__(256) void wsum(
    const unsigned short* __restrict__ XLh, const float* __restrict__ csrc,
    float* __restrict__ S, int n)
{
    const int sub = threadIdx.x & 15;
    const int grp = threadIdx.x >> 4;
    const int strd = gridDim.x * 16;

    float acc[8] = {0,0,0,0,0,0,0,0};
    for (int j = blockIdx.x * 16 + grp; j < n; j += strd) {
        float cj = csrc[j];
        uint4 u = *(const uint4*)&XLh[(size_t)j * 128 + sub * 8];
        float f0,f1,f2,f3,f4,f5,f6,f7;
        unpack2(u.x, f0, f1); unpack2(u.y, f2, f3);
        unpack2(u.z, f4, f5); unpack2(u.w, f6, f7);
        acc[0] += cj*f0; acc[1] += cj*f1; acc[2] += cj*f2; acc[3] += cj*f3;
        acc[4] += cj*f4; acc[5] += cj*f5; acc[6] += cj*f6; acc[7] += cj*f7;
    }

    __shared__ float sb[16][128];
    #pragma unroll
    for (int k = 0; k < 8; k += 4)
        *(float4*)&sb[grp][sub * 8 + k] = make_float4(acc[k], acc[k+1], acc[k+2], acc[k+3]);
    __syncthreads();

    if (threadIdx.x < 128) {
        float t = 0.f;
        #pragma unroll
        for (int g = 0; g < 16; ++g) t += sb[g][threadIdx.x];
        atomicAdd(&S[threadIdx.x], t);
    }
}

// ---------------------------------------------------------------------------
// K4: g = BN_affine(S/n + bias1); out = softmax(g @ Wc + bc)
// ---------------------------------------------------------------------------
__global__ __launch_bounds__(128) void finalize(
    const float* __restrict__ S, const float* __restrict__ bias1,
    const float* __restrict__ gamma, const float* __restrict__ beta,
    const float* __restrict__ mean, const float* __restrict__ var,
    const float* __restrict__ Wc, const float* __restrict__ bc,
    float* __restrict__ out, int n)
{
    __shared__ float g[128];
    __shared__ float lg[5];
    const int t = threadIdx.x;

    float gv = (S[t] / (float)n + bias1[t] - mean[t])
             * rsqrtf(var[t] + 1e-5f) * gamma[t] + beta[t];
    g[t] = gv;
    __syncthreads();

    if (t < 5) {
        float acc = bc[t];
        #pragma unroll 16
        for (int d = 0; d < 128; ++d) acc += g[d] * Wc[d * 5 + t];
        lg[t] = acc;
    }
    __syncthreads();

    if (t == 0) {
        float m = lg[0];
        #pragma unroll
        for (int i = 1; i < 5; ++i) m = fmaxf(m, lg[i]);
        float ex[5]; float sum = 0.f;
        #pragma unroll
        for (int i = 0; i < 5; ++i) { ex[i] = expf(lg[i] - m); sum += ex[i]; }
        #pragma unroll
        for (int i = 0; i < 5; ++i) out[i] = ex[i] / sum;
    }
}

// ---------------------------------------------------------------------------
extern "C" void kernel_launch(void* const* d_in, const int* in_sizes, int n_in,
                              void* d_out, int out_size, void* d_ws, size_t ws_size,
                              hipStream_t stream)
{
    const float* x     = (const float*)d_in[0];
    const int*   ei    = (const int*)  d_in[1];
    const float* Wl    = (const float*)d_in[2];
    const float* bl    = (const float*)d_in[3];
    const float* Wr    = (const float*)d_in[4];
    const float* br    = (const float*)d_in[5];
    const float* att   = (const float*)d_in[6];
    const float* bias1 = (const float*)d_in[7];
    const float* gamma = (const float*)d_in[8];
    const float* beta  = (const float*)d_in[9];
    const float* mean  = (const float*)d_in[10];
    const float* var   = (const float*)d_in[11];
    const float* Wc    = (const float*)d_in[12];
    const float* bc    = (const float*)d_in[13];

    const int n    = in_sizes[0] / 128;
    const int nE   = in_sizes[1] / 2;
    const int nTot = nE + n;

    unsigned short* XLh = (unsigned short*)d_ws;            // n*128 bf16
    unsigned short* XRh = XLh + (size_t)n * 128;            // n*128 bf16
    unsigned short* Whf = XRh + (size_t)n * 128;            // 32768 bf16
    float* bh    = (float*)(Whf + 32768);                   // 256
    float* wbuf  = bh + 256;                                // nTot
    float* denom = wbuf + nTot;                             // n
    float* csrc  = denom + n;                               // n
    float* S     = csrc + n;                                // 128

    hipMemsetAsync(denom, 0, (size_t)(2 * n + 128) * sizeof(float), stream);

    prep<<<129, 256, 0, stream>>>(Wl, bl, Wr, br, Whf, bh);

    const int ntiles = (n + GBM - 1) / GBM;
    gemm_mfma<<<512, 256, 0, stream>>>(x, Whf, bh, XLh, XRh, n, ntiles);

    edge_logits<<<(nTot * 16 + 255) / 256, 256, 0, stream>>>(
        XLh, XRh, ei, att, wbuf, denom, nE, nTot);

    edge_coeff<<<(nTot + 255) / 256, 256, 0, stream>>>(ei, wbuf, denom, csrc, nE, nTot);

    wsum<<<512, 256, 0, stream>>>(XLh, csrc, S, n);

    finalize<<<1, 128, 0, stream>>>(S, bias1, gamma, beta, mean, var, Wc, bc,
                                    (float*)d_out, n);
}

// Round 4
// 108.409 us; speedup vs baseline: 2.0321x; 1.0925x over previous
//
#include <hip/hip_runtime.h>
#include <hip/hip_bf16.h>

typedef __attribute__((ext_vector_type(8))) short short8v;
typedef __attribute__((ext_vector_type(4))) float f32x4;
typedef __attribute__((ext_vector_type(2))) float v2f;

__device__ __forceinline__ unsigned short f2b(float f) {
    union { float f; unsigned int u; } v; v.f = f;
    unsigned int r = (v.u + 0x7fffu + ((v.u >> 16) & 1u)) >> 16;
    return (unsigned short)r;
}
__device__ __forceinline__ unsigned int pack2(float lo, float hi) {
    return (unsigned int)f2b(lo) | ((unsigned int)f2b(hi) << 16);
}

// fp8 e4m3 helpers (HW convert; pack/unpack both HW => self-consistent)
__device__ __forceinline__ unsigned int pk_fp8x4(float a, float b, float c, float d) {
    unsigned int u = __builtin_amdgcn_cvt_pk_fp8_f32(a, b, 0u, false);
    u = __builtin_amdgcn_cvt_pk_fp8_f32(c, d, u, true);
    return u;
}
__device__ __forceinline__ void unpk_fp8x4(unsigned int u, float* o) {
    v2f lo = __builtin_amdgcn_cvt_pk_f32_fp8(u, false);
    v2f hi = __builtin_amdgcn_cvt_pk_f32_fp8(u, true);
    o[0] = lo[0]; o[1] = lo[1]; o[2] = hi[0]; o[3] = hi[1];
}

// ---------------------------------------------------------------------------
// K0: pack Wl|Wr into bf16 MFMA-B-fragment order Whf, bh = bl|br,
//     and zero zbuf[0..nz) (denom/csrc/S scratch).
// ---------------------------------------------------------------------------
__global__ __launch_bounds__(256) void prep(
    const float* __restrict__ Wl, const float* __restrict__ bl,
    const float* __restrict__ Wr, const float* __restrict__ br,
    unsigned short* __restrict__ Whf, float* __restrict__ bh,
    float* __restrict__ zbuf, int nz)
{
    const int idx    = blockIdx.x * 256 + threadIdx.x;
    const int stride = gridDim.x * 256;

    for (int i = idx; i < 32768; i += stride) {
        int j   = i & 7;
        int l   = (i >> 3) & 63;
        int nfg = (i >> 9) & 15;
        int ks  = i >> 13;
        int k = ks * 32 + (l >> 4) * 8 + j;
        int c = nfg * 16 + (l & 15);
        float v = (c < 128) ? Wl[k * 128 + c] : Wr[k * 128 + (c - 128)];
        Whf[i] = f2b(v);
    }
    if (idx < 256) bh[idx] = (idx < 128) ? bl[idx] : br[idx - 128];
    for (int i = idx; i < nz; i += stride) zbuf[i] = 0.f;
}

// ---------------------------------------------------------------------------
// K1: [XLq|XRq] = fp8(x @ [Wl|Wr] + [bl|br]) via bf16 MFMA.
// 256 thr (4 waves), tile 64 rows x 256 cols, K=128. B-frags in registers.
// ---------------------------------------------------------------------------
#define GBM 64
__global__ __launch_bounds__(256) void gemm_mfma(
    const float* __restrict__ x, const unsigned short* __restrict__ Whf,
    const float* __restrict__ bh,
    unsigned char* __restrict__ XLq, unsigned char* __restrict__ XRq,
    int n, int ntiles)
{
    __shared__ unsigned short xs[GBM * 128];   // 16 KB, swizzled

    const int tid = threadIdx.x;
    const int w   = tid >> 6;
    const int l   = tid & 63;
    const int lr  = l & 15;
    const int lk  = l >> 4;

    short8v B[4][4];
    #pragma unroll
    for (int ks = 0; ks < 4; ++ks)
        #pragma unroll
        for (int nf = 0; nf < 4; ++nf)
            B[ks][nf] = *(const short8v*)&Whf[(((ks * 16 + (w * 4 + nf)) * 64 + l) << 3)];

    float biasv[4];
    #pragma unroll
    for (int nf = 0; nf < 4; ++nf) biasv[nf] = bh[w * 64 + nf * 16 + lr];

    const int sr  = tid >> 2;
    const int sc0 = (tid & 3) * 32;
    const int swz = (sr & 7) << 4;

    for (int tile = blockIdx.x; tile < ntiles; tile += gridDim.x) {
        const int row0 = tile * GBM;

        {
            const int grow = row0 + sr;
            if (grow < n) {
                const float4* src = (const float4*)&x[(size_t)grow * 128 + sc0];
                #pragma unroll
                for (int i = 0; i < 8; ++i) {
                    float4 v = src[i];
                    uint2 p; p.x = pack2(v.x, v.y); p.y = pack2(v.z, v.w);
                    int byte = (sc0 + i * 4) * 2;
                    *(uint2*)((char*)xs + sr * 256 + (byte ^ swz)) = p;
                }
            } else {
                uint2 p{0, 0};
                #pragma unroll
                for (int i = 0; i < 8; ++i) {
                    int byte = (sc0 + i * 4) * 2;
                    *(uint2*)((char*)xs + sr * 256 + (byte ^ swz)) = p;
                }
            }
        }
        __syncthreads();

        f32x4 acc[4][4];
        #pragma unroll
        for (int mf = 0; mf < 4; ++mf)
            #pragma unroll
            for (int nf = 0; nf < 4; ++nf)
                acc[mf][nf] = f32x4{0.f, 0.f, 0.f, 0.f};

        #pragma unroll
        for (int ks = 0; ks < 4; ++ks) {
            short8v A[4];
            #pragma unroll
            for (int mf = 0; mf < 4; ++mf) {
                int rr = mf * 16 + lr;
                int byte = (ks * 32 + lk * 8) * 2;
                A[mf] = *(short8v*)((char*)xs + rr * 256 + (byte ^ ((rr & 7) << 4)));
            }
            #pragma unroll
            for (int mf = 0; mf < 4; ++mf)
                #pragma unroll
                for (int nf = 0; nf < 4; ++nf)
                    acc[mf][nf] = __builtin_amdgcn_mfma_f32_16x16x32_bf16(
                        A[mf], B[ks][nf], acc[mf][nf], 0, 0, 0);
        }

        // epilogue: bias + fp8 store. C/D: col=lane&15, row=lk*4+j
        unsigned char* O   = (w < 2) ? XLq : XRq;
        const int      oc0 = (w < 2) ? w * 64 : (w - 2) * 64;
        #pragma unroll
        for (int mf = 0; mf < 4; ++mf) {
            #pragma unroll
            for (int nf = 0; nf < 4; ++nf) {
                const int ocol = oc0 + nf * 16 + lr;
                #pragma unroll
                for (int j = 0; j < 4; ++j) {
                    int grow = row0 + mf * 16 + lk * 4 + j;
                    if (grow < n) {
                        unsigned int u = __builtin_amdgcn_cvt_pk_fp8_f32(
                            acc[mf][nf][j] + biasv[nf], 0.f, 0u, false);
                        O[(size_t)grow * 128 + ocol] = (unsigned char)u;
                    }
                }
            }
        }
        __syncthreads();
    }
}

// ---------------------------------------------------------------------------
// K2: per edge: logit = att . lrelu(xl[src]+xr[dst]); w=exp(logit);
//     denom[dst] += w.  8 lanes/edge, fp8 gathers (128B/row).
// ---------------------------------------------------------------------------
__global__ __launch_bounds__(256) void edge_logits(
    const unsigned char* __restrict__ XLq, const unsigned char* __restrict__ XRq,
    const int* __restrict__ ei, const float* __restrict__ att,
    float* __restrict__ wbuf, float* __restrict__ denom,
    int nE, int nTot)
{
    const int e = (blockIdx.x * 256 + threadIdx.x) >> 3;
    if (e >= nTot) return;
    const int sub = threadIdx.x & 7;

    int src, dst;
    if (e < nE) { src = ei[e]; dst = ei[nE + e]; }
    else        { src = dst = e - nE; }

    uint4 ul = *(const uint4*)&XLq[(size_t)src * 128 + sub * 16];
    uint4 ur = *(const uint4*)&XRq[(size_t)dst * 128 + sub * 16];

    float fl[16], fr[16];
    unpk_fp8x4(ul.x, fl + 0); unpk_fp8x4(ul.y, fl + 4);
    unpk_fp8x4(ul.z, fl + 8); unpk_fp8x4(ul.w, fl + 12);
    unpk_fp8x4(ur.x, fr + 0); unpk_fp8x4(ur.y, fr + 4);
    unpk_fp8x4(ur.z, fr + 8); unpk_fp8x4(ur.w, fr + 12);

    const float4* ap = (const float4*)&att[sub * 16];
    float p = 0.f;
    #pragma unroll
    for (int q = 0; q < 4; ++q) {
        float4 a = ap[q];
        float s0 = fl[q*4+0] + fr[q*4+0];
        float s1 = fl[q*4+1] + fr[q*4+1];
        float s2 = fl[q*4+2] + fr[q*4+2];
        float s3 = fl[q*4+3] + fr[q*4+3];
        s0 = s0 > 0.f ? s0 : 0.2f*s0;  s1 = s1 > 0.f ? s1 : 0.2f*s1;
        s2 = s2 > 0.f ? s2 : 0.2f*s2;  s3 = s3 > 0.f ? s3 : 0.2f*s3;
        p += s0*a.x + s1*a.y + s2*a.z + s3*a.w;
    }

    #pragma unroll
    for (int m = 4; m >= 1; m >>= 1) p += __shfl_xor(p, m);

    if (sub == 0) {
        float wv = __expf(p);     // logits O(1); softmax shift-invariant
        wbuf[e] = wv;
        atomicAdd(&denom[dst], wv);
    }
}

// ---------------------------------------------------------------------------
// K3a: c[src] += w[e] / denom[dst]
// ---------------------------------------------------------------------------
__global__ __launch_bounds__(256) void edge_coeff(
    const int* __restrict__ ei, const float* __restrict__ wbuf,
    const float* __restrict__ denom, float* __restrict__ csrc,
    int nE, int nTot)
{
    const int e = blockIdx.x * 256 + threadIdx.x;
    if (e >= nTot) return;
    int src, dst;
    if (e < nE) { src = ei[e]; dst = ei[nE + e]; }
    else        { src = dst = e - nE; }
    atomicAdd(&csrc[src], wbuf[e] / denom[dst]);
}

// ---------------------------------------------------------------------------
// K3b: S = sum_j c[j] * xl[j]   (dense fp8 stream)
// ---------------------------------------------------------------------------
__global__ __launch_bounds__(256) void wsum(
    const unsigned char* __restrict__ XLq, const float* __restrict__ csrc,
    float* __restrict__ S, int n)
{
    const int sub = threadIdx.x & 7;       // 16 features each
    const int grp = threadIdx.x >> 3;      // 32 nodes per block slice
    const int strd = gridDim.x * 32;

    float acc[16];
    #pragma unroll
    for (int k = 0; k < 16; ++k) acc[k] = 0.f;

    for (int j = blockIdx.x * 32 + grp; j < n; j += strd) {
        float cj = csrc[j];
        uint4 u = *(const uint4*)&XLq[(size_t)j * 128 + sub * 16];
        float f[16];
        unpk_fp8x4(u.x, f + 0); unpk_fp8x4(u.y, f + 4);
        unpk_fp8x4(u.z, f + 8); unpk_fp8x4(u.w, f + 12);
        #pragma unroll
        for (int k = 0; k < 16; ++k) acc[k] += cj * f[k];
    }

    __shared__ float sb[32][128];
    #pragma unroll
    for (int k = 0; k < 16; k += 4)
        *(float4*)&sb[grp][sub * 16 + k] = make_float4(acc[k], acc[k+1], acc[k+2], acc[k+3]);
    __syncthreads();

    if (threadIdx.x < 128) {
        float t = 0.f;
        #pragma unroll
        for (int g = 0; g < 32; ++g) t += sb[g][threadIdx.x];
        atomicAdd(&S[threadIdx.x], t);
    }
}

// ---------------------------------------------------------------------------
// K4: g = BN_affine(S/n + bias1); out = softmax(g @ Wc + bc)
// ---------------------------------------------------------------------------
__global__ __launch_bounds__(128) void finalize(
    const float* __restrict__ S, const float* __restrict__ bias1,
    const float* __restrict__ gamma, const float* __restrict__ beta,
    const float* __restrict__ mean, const float* __restrict__ var,
    const float* __restrict__ Wc, const float* __restrict__ bc,
    float* __restrict__ out, int n)
{
    __shared__ float g[128];
    __shared__ float lg[5];
    const int t = threadIdx.x;

    float gv = (S[t] / (float)n + bias1[t] - mean[t])
             * rsqrtf(var[t] + 1e-5f) * gamma[t] + beta[t];
    g[t] = gv;
    __syncthreads();

    if (t < 5) {
        float acc = bc[t];
        #pragma unroll 16
        for (int d = 0; d < 128; ++d) acc += g[d] * Wc[d * 5 + t];
        lg[t] = acc;
    }
    __syncthreads();

    if (t == 0) {
        float m = lg[0];
        #pragma unroll
        for (int i = 1; i < 5; ++i) m = fmaxf(m, lg[i]);
        float ex[5]; float sum = 0.f;
        #pragma unroll
        for (int i = 0; i < 5; ++i) { ex[i] = expf(lg[i] - m); sum += ex[i]; }
        #pragma unroll
        for (int i = 0; i < 5; ++i) out[i] = ex[i] / sum;
    }
}

// ---------------------------------------------------------------------------
extern "C" void kernel_launch(void* const* d_in, const int* in_sizes, int n_in,
                              void* d_out, int out_size, void* d_ws, size_t ws_size,
                              hipStream_t stream)
{
    const float* x     = (const float*)d_in[0];
    const int*   ei    = (const int*)  d_in[1];
    const float* Wl    = (const float*)d_in[2];
    const float* bl    = (const float*)d_in[3];
    const float* Wr    = (const float*)d_in[4];
    const float* br    = (const float*)d_in[5];
    const float* att   = (const float*)d_in[6];
    const float* bias1 = (const float*)d_in[7];
    const float* gamma = (const float*)d_in[8];
    const float* beta  = (const float*)d_in[9];
    const float* mean  = (const float*)d_in[10];
    const float* var   = (const float*)d_in[11];
    const float* Wc    = (const float*)d_in[12];
    const float* bc    = (const float*)d_in[13];

    const int n    = in_sizes[0] / 128;
    const int nE   = in_sizes[1] / 2;
    const int nTot = nE + n;

    unsigned char* XLq = (unsigned char*)d_ws;              // n*128 fp8
    unsigned char* XRq = XLq + (size_t)n * 128;             // n*128 fp8
    unsigned short* Whf = (unsigned short*)(XRq + (size_t)n * 128); // 32768 bf16
    float* bh    = (float*)(Whf + 32768);                   // 256
    float* wbuf  = bh + 256;                                // nTot
    float* denom = wbuf + nTot;                             // n
    float* csrc  = denom + n;                               // n
    float* S     = csrc + n;                                // 128

    // prep packs W, concats bias, and zeroes denom+csrc+S (no hipMemset!)
    prep<<<512, 256, 0, stream>>>(Wl, bl, Wr, br, Whf, bh, denom, 2 * n + 128);

    const int ntiles = (n + GBM - 1) / GBM;
    gemm_mfma<<<512, 256, 0, stream>>>(x, Whf, bh, XLq, XRq, n, ntiles);

    edge_logits<<<(nTot * 8 + 255) / 256, 256, 0, stream>>>(
        XLq, XRq, ei, att, wbuf, denom, nE, nTot);

    edge_coeff<<<(nTot + 255) / 256, 256, 0, stream>>>(ei, wbuf, denom, csrc, nE, nTot);

    wsum<<<512, 256, 0, stream>>>(XLq, csrc, S, n);

    finalize<<<1, 128, 0, stream>>>(S, bias1, gamma, beta, mean, var, Wc, bc,
                                    (float*)d_out, n);
}

// Round 5
// 106.216 us; speedup vs baseline: 2.0741x; 1.0206x over previous
//
#include <hip/hip_runtime.h>
#include <hip/hip_bf16.h>

typedef __attribute__((ext_vector_type(8))) short short8v;
typedef __attribute__((ext_vector_type(4))) float f32x4;
typedef __attribute__((ext_vector_type(2))) float v2f;

__device__ __forceinline__ unsigned short f2b(float f) {
    union { float f; unsigned int u; } v; v.f = f;
    unsigned int r = (v.u + 0x7fffu + ((v.u >> 16) & 1u)) >> 16;
    return (unsigned short)r;
}
__device__ __forceinline__ unsigned int pack2(float lo, float hi) {
    return (unsigned int)f2b(lo) | ((unsigned int)f2b(hi) << 16);
}
__device__ __forceinline__ void unpk_fp8x4(unsigned int u, float* o) {
    v2f lo = __builtin_amdgcn_cvt_pk_f32_fp8(u, false);
    v2f hi = __builtin_amdgcn_cvt_pk_f32_fp8(u, true);
    o[0] = lo[0]; o[1] = lo[1]; o[2] = hi[0]; o[3] = hi[1];
}

// ---------------------------------------------------------------------------
// K0: pack Wl|Wr into bf16 MFMA-B-fragment order Whf, bh = bl|br,
//     and zero zbuf[0..nz) (denom/csrc/S scratch).
// ---------------------------------------------------------------------------
__global__ __launch_bounds__(256) void prep(
    const float* __restrict__ Wl, const float* __restrict__ bl,
    const float* __restrict__ Wr, const float* __restrict__ br,
    unsigned short* __restrict__ Whf, float* __restrict__ bh,
    float* __restrict__ zbuf, int nz)
{
    const int idx    = blockIdx.x * 256 + threadIdx.x;
    const int stride = gridDim.x * 256;

    for (int i = idx; i < 32768; i += stride) {
        int j   = i & 7;
        int l   = (i >> 3) & 63;
        int nfg = (i >> 9) & 15;
        int ks  = i >> 13;
        int k = ks * 32 + (l >> 4) * 8 + j;
        int c = nfg * 16 + (l & 15);
        float v = (c < 128) ? Wl[k * 128 + c] : Wr[k * 128 + (c - 128)];
        Whf[i] = f2b(v);
    }
    if (idx < 256) bh[idx] = (idx < 128) ? bl[idx] : br[idx - 128];
    for (int i = idx; i < nz; i += stride) zbuf[i] = 0.f;
}

// ---------------------------------------------------------------------------
// K1: [XLq|XRq] = fp8(x @ [Wl|Wr] + [bl|br]) via bf16 MFMA.
// 256 thr (4 waves). Grid = ntiles, ONE 64x256 tile per block.
// Epilogue goes through LDS so global stores are coalesced uint4.
// ---------------------------------------------------------------------------
#define GBM 64
__global__ __launch_bounds__(256) void gemm_mfma(
    const float* __restrict__ x, const unsigned short* __restrict__ Whf,
    const float* __restrict__ bh,
    unsigned char* __restrict__ XLq, unsigned char* __restrict__ XRq,
    int n)
{
    __shared__ unsigned short xs[GBM * 128];     // 16 KB A-tile (swizzled)
    __shared__ unsigned char  lbuf[GBM][256];    // 16 KB fp8 C-tile

    const int tid = threadIdx.x;
    const int w   = tid >> 6;
    const int l   = tid & 63;
    const int lr  = l & 15;
    const int lk  = l >> 4;

    short8v B[4][4];
    #pragma unroll
    for (int ks = 0; ks < 4; ++ks)
        #pragma unroll
        for (int nf = 0; nf < 4; ++nf)
            B[ks][nf] = *(const short8v*)&Whf[(((ks * 16 + (w * 4 + nf)) * 64 + l) << 3)];

    float biasv[4];
    #pragma unroll
    for (int nf = 0; nf < 4; ++nf) biasv[nf] = bh[w * 64 + nf * 16 + lr];

    const int sr  = tid >> 2;
    const int sc0 = (tid & 3) * 32;
    const int swz = (sr & 7) << 4;
    const int row0 = blockIdx.x * GBM;

    // ---- stage x tile (fp32 -> bf16, swizzled) ----
    {
        const int grow = row0 + sr;
        if (grow < n) {
            const float4* src = (const float4*)&x[(size_t)grow * 128 + sc0];
            #pragma unroll
            for (int i = 0; i < 8; ++i) {
                float4 v = src[i];
                uint2 p; p.x = pack2(v.x, v.y); p.y = pack2(v.z, v.w);
                int byte = (sc0 + i * 4) * 2;
                *(uint2*)((char*)xs + sr * 256 + (byte ^ swz)) = p;
            }
        } else {
            uint2 p{0, 0};
            #pragma unroll
            for (int i = 0; i < 8; ++i) {
                int byte = (sc0 + i * 4) * 2;
                *(uint2*)((char*)xs + sr * 256 + (byte ^ swz)) = p;
            }
        }
    }
    __syncthreads();

    // ---- MFMA ----
    f32x4 acc[4][4];
    #pragma unroll
    for (int mf = 0; mf < 4; ++mf)
        #pragma unroll
        for (int nf = 0; nf < 4; ++nf)
            acc[mf][nf] = f32x4{0.f, 0.f, 0.f, 0.f};

    #pragma unroll
    for (int ks = 0; ks < 4; ++ks) {
        short8v A[4];
        #pragma unroll
        for (int mf = 0; mf < 4; ++mf) {
            int rr = mf * 16 + lr;
            int byte = (ks * 32 + lk * 8) * 2;
            A[mf] = *(short8v*)((char*)xs + rr * 256 + (byte ^ ((rr & 7) << 4)));
        }
        #pragma unroll
        for (int mf = 0; mf < 4; ++mf)
            #pragma unroll
            for (int nf = 0; nf < 4; ++nf)
                acc[mf][nf] = __builtin_amdgcn_mfma_f32_16x16x32_bf16(
                    A[mf], B[ks][nf], acc[mf][nf], 0, 0, 0);
    }

    // ---- epilogue: bias + fp8 into LDS (disjoint buffer, no sync needed) ----
    // C/D: col = lane&15, row = lk*4 + j
    #pragma unroll
    for (int mf = 0; mf < 4; ++mf) {
        #pragma unroll
        for (int nf = 0; nf < 4; ++nf) {
            const int ocol = w * 64 + nf * 16 + lr;   // 0..255
            #pragma unroll
            for (int j = 0; j < 4; ++j) {
                unsigned int u = __builtin_amdgcn_cvt_pk_fp8_f32(
                    acc[mf][nf][j] + biasv[nf], 0.f, 0u, false);
                lbuf[mf * 16 + lk * 4 + j][ocol] = (unsigned char)u;
            }
        }
    }
    __syncthreads();

    // ---- coalesced stores: 1024 chunks of 16B, 4 per thread ----
    #pragma unroll
    for (int k = 0; k < 4; ++k) {
        const int ch  = k * 256 + tid;
        const int row = ch >> 4;
        const int seg = ch & 15;
        const int grow = row0 + row;
        if (grow < n) {
            uint4 v = *(const uint4*)&lbuf[row][seg * 16];
            if (seg < 8) *(uint4*)&XLq[(size_t)grow * 128 + seg * 16] = v;
            else         *(uint4*)&XRq[(size_t)grow * 128 + (seg - 8) * 16] = v;
        }
    }
}

// ---------------------------------------------------------------------------
// K2: per edge: logit = att . lrelu(xl[src]+xr[dst]); w=exp(logit);
//     denom[dst] += w.  8 lanes/edge, fp8 gathers (128B/row).
// ---------------------------------------------------------------------------
__global__ __launch_bounds__(256) void edge_logits(
    const unsigned char* __restrict__ XLq, const unsigned char* __restrict__ XRq,
    const int* __restrict__ ei, const float* __restrict__ att,
    float* __restrict__ wbuf, float* __restrict__ denom,
    int nE, int nTot)
{
    const int e = (blockIdx.x * 256 + threadIdx.x) >> 3;
    if (e >= nTot) return;
    const int sub = threadIdx.x & 7;

    int src, dst;
    if (e < nE) { src = ei[e]; dst = ei[nE + e]; }
    else        { src = dst = e - nE; }

    uint4 ul = *(const uint4*)&XLq[(size_t)src * 128 + sub * 16];
    uint4 ur = *(const uint4*)&XRq[(size_t)dst * 128 + sub * 16];

    float fl[16], fr[16];
    unpk_fp8x4(ul.x, fl + 0); unpk_fp8x4(ul.y, fl + 4);
    unpk_fp8x4(ul.z, fl + 8); unpk_fp8x4(ul.w, fl + 12);
    unpk_fp8x4(ur.x, fr + 0); unpk_fp8x4(ur.y, fr + 4);
    unpk_fp8x4(ur.z, fr + 8); unpk_fp8x4(ur.w, fr + 12);

    const float4* ap = (const float4*)&att[sub * 16];
    float p = 0.f;
    #pragma unroll
    for (int q = 0; q < 4; ++q) {
        float4 a = ap[q];
        float s0 = fl[q*4+0] + fr[q*4+0];
        float s1 = fl[q*4+1] + fr[q*4+1];
        float s2 = fl[q*4+2] + fr[q*4+2];
        float s3 = fl[q*4+3] + fr[q*4+3];
        s0 = s0 > 0.f ? s0 : 0.2f*s0;  s1 = s1 > 0.f ? s1 : 0.2f*s1;
        s2 = s2 > 0.f ? s2 : 0.2f*s2;  s3 = s3 > 0.f ? s3 : 0.2f*s3;
        p += s0*a.x + s1*a.y + s2*a.z + s3*a.w;
    }

    #pragma unroll
    for (int m = 4; m >= 1; m >>= 1) p += __shfl_xor(p, m);

    if (sub == 0) {
        float wv = __expf(p);     // logits O(1); softmax shift-invariant
        wbuf[e] = wv;
        atomicAdd(&denom[dst], wv);
    }
}

// ---------------------------------------------------------------------------
// K3a: c[src] += w[e] / denom[dst]
// ---------------------------------------------------------------------------
__global__ __launch_bounds__(256) void edge_coeff(
    const int* __restrict__ ei, const float* __restrict__ wbuf,
    const float* __restrict__ denom, float* __restrict__ csrc,
    int nE, int nTot)
{
    const int e = blockIdx.x * 256 + threadIdx.x;
    if (e >= nTot) return;
    int src, dst;
    if (e < nE) { src = ei[e]; dst = ei[nE + e]; }
    else        { src = dst = e - nE; }
    atomicAdd(&csrc[src], wbuf[e] / denom[dst]);
}

// ---------------------------------------------------------------------------
// K3b: S = sum_j c[j] * xl[j]   (dense fp8 stream)
// ---------------------------------------------------------------------------
__global__ __launch_bounds__(256) void wsum(
    const unsigned char* __restrict__ XLq, const float* __restrict__ csrc,
    float* __restrict__ S, int n)
{
    const int sub = threadIdx.x & 7;       // 16 features each
    const int grp = threadIdx.x >> 3;      // 32 nodes per block slice
    const int strd = gridDim.x * 32;

    float acc[16];
    #pragma unroll
    for (int k = 0; k < 16; ++k) acc[k] = 0.f;

    for (int j = blockIdx.x * 32 + grp; j < n; j += strd) {
        float cj = csrc[j];
        uint4 u = *(const uint4*)&XLq[(size_t)j * 128 + sub * 16];
        float f[16];
        unpk_fp8x4(u.x, f + 0); unpk_fp8x4(u.y, f + 4);
        unpk_fp8x4(u.z, f + 8); unpk_fp8x4(u.w, f + 12);
        #pragma unroll
        for (int k = 0; k < 16; ++k) acc[k] += cj * f[k];
    }

    __shared__ float sb[32][128];
    #pragma unroll
    for (int k = 0; k < 16; k += 4)
        *(float4*)&sb[grp][sub * 16 + k] = make_float4(acc[k], acc[k+1], acc[k+2], acc[k+3]);
    __syncthreads();

    if (threadIdx.x < 128) {
        float t = 0.f;
        #pragma unroll
        for (int g = 0; g < 32; ++g) t += sb[g][threadIdx.x];
        atomicAdd(&S[threadIdx.x], t);
    }
}

// ---------------------------------------------------------------------------
// K4: g = BN_affine(S/n + bias1); out = softmax(g @ Wc + bc)
// ---------------------------------------------------------------------------
__global__ __launch_bounds__(128) void finalize(
    const float* __restrict__ S, const float* __restrict__ bias1,
    const float* __restrict__ gamma, const float* __restrict__ beta,
    const float* __restrict__ mean, const float* __restrict__ var,
    const float* __restrict__ Wc, const float* __restrict__ bc,
    float* __restrict__ out, int n)
{
    __shared__ float g[128];
    __shared__ float lg[5];
    const int t = threadIdx.x;

    float gv = (S[t] / (float)n + bias1[t] - mean[t])
             * rsqrtf(var[t] + 1e-5f) * gamma[t] + beta[t];
    g[t] = gv;
    __syncthreads();

    if (t < 5) {
        float acc = bc[t];
        #pragma unroll 16
        for (int d = 0; d < 128; ++d) acc += g[d] * Wc[d * 5 + t];
        lg[t] = acc;
    }
    __syncthreads();

    if (t == 0) {
        float m = lg[0];
        #pragma unroll
        for (int i = 1; i < 5; ++i) m = fmaxf(m, lg[i]);
        float ex[5]; float sum = 0.f;
        #pragma unroll
        for (int i = 0; i < 5; ++i) { ex[i] = expf(lg[i] - m); sum += ex[i]; }
        #pragma unroll
        for (int i = 0; i < 5; ++i) out[i] = ex[i] / sum;
    }
}

// ---------------------------------------------------------------------------
extern "C" void kernel_launch(void* const* d_in, const int* in_sizes, int n_in,
                              void* d_out, int out_size, void* d_ws, size_t ws_size,
                              hipStream_t stream)
{
    const float* x     = (const float*)d_in[0];
    const int*   ei    = (const int*)  d_in[1];
    const float* Wl    = (const float*)d_in[2];
    const float* bl    = (const float*)d_in[3];
    const float* Wr    = (const float*)d_in[4];
    const float* br    = (const float*)d_in[5];
    const float* att   = (const float*)d_in[6];
    const float* bias1 = (const float*)d_in[7];
    const float* gamma = (const float*)d_in[8];
    const float* beta  = (const float*)d_in[9];
    const float* mean  = (const float*)d_in[10];
    const float* var   = (const float*)d_in[11];
    const float* Wc    = (const float*)d_in[12];
    const float* bc    = (const float*)d_in[13];

    const int n    = in_sizes[0] / 128;
    const int nE   = in_sizes[1] / 2;
    const int nTot = nE + n;

    unsigned char* XLq = (unsigned char*)d_ws;              // n*128 fp8
    unsigned char* XRq = XLq + (size_t)n * 128;             // n*128 fp8
    unsigned short* Whf = (unsigned short*)(XRq + (size_t)n * 128); // 32768 bf16
    float* bh    = (float*)(Whf + 32768);                   // 256
    float* wbuf  = bh + 256;                                // nTot
    float* denom = wbuf + nTot;                             // n
    float* csrc  = denom + n;                               // n
    float* S     = csrc + n;                                // 128

    // prep packs W, concats bias, and zeroes denom+csrc+S
    prep<<<512, 256, 0, stream>>>(Wl, bl, Wr, br, Whf, bh, denom, 2 * n + 128);

    const int ntiles = (n + GBM - 1) / GBM;
    gemm_mfma<<<ntiles, 256, 0, stream>>>(x, Whf, bh, XLq, XRq, n);

    edge_logits<<<(nTot * 8 + 255) / 256, 256, 0, stream>>>(
        XLq, XRq, ei, att, wbuf, denom, nE, nTot);

    edge_coeff<<<(nTot + 255) / 256, 256, 0, stream>>>(ei, wbuf, denom, csrc, nE, nTot);

    wsum<<<512, 256, 0, stream>>>(XLq, csrc, S, n);

    finalize<<<1, 128, 0, stream>>>(S, bias1, gamma, beta, mean, var, Wc, bc,
                                    (float*)d_out, n);
}